// Round 12
// baseline (796.582 us; speedup 1.0000x reference)
//
#include <hip/hip_runtime.h>
#include <cstdint>

#define TT 300   // timesteps
#define TC 75    // TT/4
#define NBATCH 4

// PSP + refractory IIR step, exact op order of the reference scan.
__device__ __forceinline__ void psp_step(float z, float& gp, float& hp, float& gr, float& hr, float& s_out) {
    hp = 0.90483741803595957f * (hp + gp);      // a_sr = exp(-1/10)
    gp = 0.90483741803595957f * gp + z;
    hr = 0.36787944117144233f * (hr + gr);      // a_rf = exp(-1)
    gr = 0.36787944117144233f * gr;
    float u = 0.27182818284590452f * hp + (-54.365636569180904f) * hr; // c_sr*hp + c_rf*hr
    float s = (u >= 10.0f) ? 1.0f : 0.0f;
    gr += s;
    s_out = s;
}

// Coalesced R-way partial reduce: zr[p][t] = sum_r z[r*pstride + p*TT + t].
template <int R>
__global__ void k_reduce(const float* __restrict__ z, float* __restrict__ zr,
                         int total4, int pstride) {
    int i = blockIdx.x * 256 + threadIdx.x;
    if (i >= total4) return;
    size_t pos = (size_t)i * 4;
    float4 a = *(const float4*)(z + pos);
#pragma unroll
    for (int r = 1; r < R; ++r) {
        float4 b = *(const float4*)(z + (size_t)r * pstride + pos);
        a.x += b.x; a.y += b.y; a.z += b.z; a.w += b.w;
    }
    *(float4*)(zr + pos) = a;
}

// Per-neuron scan over T with fused R-way partial reduce.
// Software-pipelined: A/B chunk double-buffer, next chunk's loads issued before the
// current chunk's ~350-cycle IIR chain (hides L2/HBM latency; FP order unchanged).
template <int R>
__global__ void k_scan_redp(const float* __restrict__ z, float* __restrict__ s,
                            int n_neur, int pstride) {
    int i = blockIdx.x * 64 + threadIdx.x;
    if (i >= n_neur) return;
    const float* zp = z + (size_t)i * TT;
    float* sp = s + (size_t)i * TT;
    float gp = 0.f, hp = 0.f, gr = 0.f, hr = 0.f;
    float4 bufA[3 * R], bufB[3 * R];
    auto loadc = [&](float4* buf, int c) {
        const float* p = zp + c * 12;
#pragma unroll
        for (int r = 0; r < R; ++r) {
            const float* pr = p + (size_t)r * pstride;
            buf[3 * r + 0] = *(const float4*)(pr);
            buf[3 * r + 1] = *(const float4*)(pr + 4);
            buf[3 * r + 2] = *(const float4*)(pr + 8);
        }
    };
    auto compute = [&](float4* buf, int c) {
        float4 a0 = buf[0], a1 = buf[1], a2 = buf[2];
#pragma unroll
        for (int r = 1; r < R; ++r) {
            a0.x += buf[3*r].x;   a0.y += buf[3*r].y;   a0.z += buf[3*r].z;   a0.w += buf[3*r].w;
            a1.x += buf[3*r+1].x; a1.y += buf[3*r+1].y; a1.z += buf[3*r+1].z; a1.w += buf[3*r+1].w;
            a2.x += buf[3*r+2].x; a2.y += buf[3*r+2].y; a2.z += buf[3*r+2].z; a2.w += buf[3*r+2].w;
        }
        float4 o0, o1, o2;
        psp_step(a0.x, gp, hp, gr, hr, o0.x);
        psp_step(a0.y, gp, hp, gr, hr, o0.y);
        psp_step(a0.z, gp, hp, gr, hr, o0.z);
        psp_step(a0.w, gp, hp, gr, hr, o0.w);
        psp_step(a1.x, gp, hp, gr, hr, o1.x);
        psp_step(a1.y, gp, hp, gr, hr, o1.y);
        psp_step(a1.z, gp, hp, gr, hr, o1.z);
        psp_step(a1.w, gp, hp, gr, hr, o1.w);
        psp_step(a2.x, gp, hp, gr, hr, o2.x);
        psp_step(a2.y, gp, hp, gr, hr, o2.y);
        psp_step(a2.z, gp, hp, gr, hr, o2.z);
        psp_step(a2.w, gp, hp, gr, hr, o2.w);
        float* q = sp + c * 12;
        *(float4*)(q) = o0;
        *(float4*)(q + 4) = o1;
        *(float4*)(q + 8) = o2;
    };
    loadc(bufA, 0);
    loadc(bufB, 1);
#pragma unroll 1
    for (int k = 0; k < 12; ++k) {
        compute(bufA, 2 * k);
        loadc(bufA, (2 * k + 2 < 25) ? 2 * k + 2 : 24);
        compute(bufB, 2 * k + 1);
        loadc(bufB, (2 * k + 3 < 25) ? 2 * k + 3 : 24);
    }
    compute(bufA, 24);
}

// Fused scan-pool-scan, thread per CONV neuron; quad pool via shfl_xor (exact on 0/1 spikes).
// Same A/B prefetch pipeline as k_scan_redp.
template <int R, int C, int H2, int W2>
__global__ void __launch_bounds__(256) k_spsq(const float* __restrict__ z,
                                              float* __restrict__ s, int pstride) {
    constexpr int H = 2 * H2, W = 2 * W2;
    int i = blockIdx.x * 256 + threadIdx.x;   // grid exact: NBATCH*C*H*W threads
    int q  = i & 3;
    int p  = i >> 2;
    int x2 = p % W2;
    int y2 = (p / W2) % H2;
    int c  = (p / (W2 * H2)) % C;
    int n  = p / (W2 * H2 * C);
    int dy = q >> 1, dx = q & 1;
    const float* zp = z + (((size_t)(n * C + c) * H + 2 * y2 + dy) * W + 2 * x2 + dx) * TT;
    float* so = s + (size_t)p * TT;
    float gp = 0.f, hp = 0.f, gr = 0.f, hr = 0.f;   // conv neuron IIR
    float Gp = 0.f, Hp = 0.f, Gr = 0.f, Hr = 0.f;   // pooled neuron IIR
    float4 bufA[3 * R], bufB[3 * R];
    auto loadc = [&](float4* buf, int cc) {
        const float* pp = zp + cc * 12;
#pragma unroll
        for (int r = 0; r < R; ++r) {
            const float* pr = pp + (size_t)r * pstride;
            buf[3 * r + 0] = *(const float4*)(pr);
            buf[3 * r + 1] = *(const float4*)(pr + 4);
            buf[3 * r + 2] = *(const float4*)(pr + 8);
        }
    };
    auto compute = [&](float4* buf, int cc) {
        float4 a0 = buf[0], a1 = buf[1], a2 = buf[2];
#pragma unroll
        for (int r = 1; r < R; ++r) {
            a0.x += buf[3*r].x;   a0.y += buf[3*r].y;   a0.z += buf[3*r].z;   a0.w += buf[3*r].w;
            a1.x += buf[3*r+1].x; a1.y += buf[3*r+1].y; a1.z += buf[3*r+1].z; a1.w += buf[3*r+1].w;
            a2.x += buf[3*r+2].x; a2.y += buf[3*r+2].y; a2.z += buf[3*r+2].z; a2.w += buf[3*r+2].w;
        }
        float zv[12] = {a0.x, a0.y, a0.z, a0.w, a1.x, a1.y, a1.z, a1.w, a2.x, a2.y, a2.z, a2.w};
        float ov[12];
#pragma unroll
        for (int tt = 0; tt < 12; ++tt) {
            float sq;
            psp_step(zv[tt], gp, hp, gr, hr, sq);
            float t1 = sq + __shfl_xor(sq, 1, 64);
            float pool = t1 + __shfl_xor(t1, 2, 64);
            psp_step(11.0f * pool, Gp, Hp, Gr, Hr, ov[tt]);
        }
        if (q == 0) {
            float* qo = so + cc * 12;
            *(float4*)(qo)     = make_float4(ov[0], ov[1], ov[2],  ov[3]);
            *(float4*)(qo + 4) = make_float4(ov[4], ov[5], ov[6],  ov[7]);
            *(float4*)(qo + 8) = make_float4(ov[8], ov[9], ov[10], ov[11]);
        }
    };
    loadc(bufA, 0);
    loadc(bufB, 1);
#pragma unroll 1
    for (int k = 0; k < 12; ++k) {
        compute(bufA, 2 * k);
        loadc(bufA, (2 * k + 2 < 25) ? 2 * k + 2 : 24);
        compute(bufB, 2 * k + 1);
        loadc(bufB, (2 * k + 3 < 25) ? 2 * k + 3 : 24);
    }
    compute(bufA, 24);
}

// Transpose-pack OIHW weights (COUT, S) -> [s][COUT] so one tap's weights are contiguous.
__global__ void k_pack_w(const float* __restrict__ w, float* __restrict__ wp, int S, int CO, int total) {
    int i = blockIdx.x * 256 + threadIdx.x;
    if (i >= total) return;
    int co = i % CO, s = i / CO;
    wp[i] = w[co * S + s];
}

// 4x4 sum-pool * 11.0 over (N,2,128,128,T) -> z (N,2,32,32,T). Thread = (p, tc), tc fastest.
__global__ void k_pool4(const float* __restrict__ x, float* __restrict__ z) {
    int idx = blockIdx.x * 256 + threadIdx.x;
    if (idx >= NBATCH * 2 * 32 * 32 * TC) return;
    int tc = idx % TC;
    int p  = idx / TC;
    int w  = p % 32;
    int h  = (p / 32) % 32;
    int nc = p / (32 * 32);
    const float* base = x + (((size_t)nc * 128 + h * 4) * 128 + w * 4) * TT + tc * 4;
    float ax = 0.f, ay = 0.f, az = 0.f, aw = 0.f;
#pragma unroll
    for (int i = 0; i < 4; ++i)
#pragma unroll
        for (int j = 0; j < 4; ++j) {
            float4 v = *(const float4*)(base + ((size_t)i * 128 + j) * TT);
            ax += v.x; ay += v.y; az += v.z; aw += v.w;
        }
    float4 o; o.x = 11.0f * ax; o.y = 11.0f * ay; o.z = 11.0f * az; o.w = 11.0f * aw;
    *(float4*)(z + (size_t)p * TT + tc * 4) = o;
}

// LDS-weight conv, 512-thread blocks (r12): LDS 36.9KB/block caps 4 blocks/CU; at 512 thr
// that's 32 waves/CU (HW max) vs 16 at 256 thr — doubles the occupancy ceiling that r11's
// counters showed as the limiter (Occ 35%, VALUBusy 61%). VGPR 60 <= 64 keeps 8 waves/SIMD.
// Thread = (sp, n, y, x, cb, tc); cb adjacent to tc. XCD swizzle (r11, FETCH 162->21MB) kept.
template <int SPLIT, int CIN, int COUT, int H, int W, int K, int PAD>
__global__ void __launch_bounds__(512) k_conv_lds(const float* __restrict__ s_in,
                                                  const float* __restrict__ wp,
                                                  float* __restrict__ z) {
    constexpr int CBN = COUT / 16;
    constexpr int CIN_SP = CIN / SPLIT;
    constexpr int S_SP = CIN_SP * K * K;
    __shared__ float wlds[S_SP * COUT];
    int nb8 = gridDim.x >> 3;
    int lb  = (blockIdx.x >> 3) + (blockIdx.x & 7) * nb8;
    int sp = (int)(((size_t)lb * 512) / (CBN * NBATCH * H * W * TC));
    {
        const float4* src = (const float4*)(wp + (size_t)sp * S_SP * COUT);
        float4* dst = (float4*)wlds;
        for (int i = threadIdx.x; i < S_SP * COUT / 4; i += 512) dst[i] = src[i];
    }
    __syncthreads();
    int t = lb * 512 + threadIdx.x;
    int tc = t % TC;     t /= TC;
    int cb = t % CBN;    t /= CBN;
    int x  = t % W;      t /= W;
    int y  = t % H;      t /= H;
    int n  = t % NBATCH;
    const float* sb = s_in + ((size_t)n * CIN + sp * CIN_SP) * H * W * TT + tc * 4;
    float acc[4][4][4]; // [cg][c][t]
#pragma unroll
    for (int a = 0; a < 4; ++a)
#pragma unroll
        for (int b = 0; b < 4; ++b)
#pragma unroll
            for (int d = 0; d < 4; ++d) acc[a][b][d] = 0.f;
#pragma unroll 1
    for (int cl = 0; cl < CIN_SP; ++cl) {
#pragma unroll
        for (int ky = 0; ky < K; ++ky) {
            int yy = y + ky - PAD;
            if (yy < 0 || yy >= H) continue;
#pragma unroll
            for (int kx = 0; kx < K; ++kx) {
                int xx = x + kx - PAD;
                if (xx < 0 || xx >= W) continue;
                float4 v = *(const float4*)(sb + ((size_t)(cl * H + yy) * W + xx) * TT);
                float va[4] = {v.x, v.y, v.z, v.w};
                const float* wrow = &wlds[((cl * K + ky) * K + kx) * COUT + cb * 16];
#pragma unroll
                for (int cg = 0; cg < 4; ++cg) {
                    float4 wv = *(const float4*)(wrow + cg * 4);
                    float wa[4] = {wv.x, wv.y, wv.z, wv.w};
#pragma unroll
                    for (int c = 0; c < 4; ++c)
#pragma unroll
                        for (int tt = 0; tt < 4; ++tt)
                            acc[cg][c][tt] += wa[c] * va[tt];
                }
            }
        }
    }
    float* zb = z + (((size_t)(sp * NBATCH + n) * COUT + cb * 16) * H * W + (size_t)y * W + x) * TT + tc * 4;
#pragma unroll
    for (int cg = 0; cg < 4; ++cg)
#pragma unroll
        for (int c = 0; c < 4; ++c) {
            float4 o; o.x = acc[cg][c][0]; o.y = acc[cg][c][1]; o.z = acc[cg][c][2]; o.w = acc[cg][c][3];
            *(float4*)(zb + (size_t)(cg * 4 + c) * H * W * TT) = o;
        }
}

// FC with f-split: partial z[sp][n][o][t] = sum_{f in chunk sp} s[n][f][t]*w[o][f].
template <int OUT, int FIN, int OPER, int FSPLIT>
__global__ void k_fc_a(const float* __restrict__ s, const float* __restrict__ wgt,
                       float* __restrict__ z) {
    constexpr int OG = OUT / OPER, FCH = FIN / FSPLIT;
    int idx = blockIdx.x * 256 + threadIdx.x;
    if (idx >= NBATCH * OG * TC * FSPLIT) return;
    int tc = idx % TC;
    int og = (idx / TC) % OG;
    int n  = (idx / (TC * OG)) % NBATCH;
    int sp = idx / (TC * OG * NBATCH);
    const float* sb = s + (size_t)n * FIN * TT + (size_t)sp * FCH * TT + tc * 4;
    const float* wb = wgt + (size_t)sp * FCH;
    float acc[OPER][4];
#pragma unroll
    for (int k = 0; k < OPER; ++k) { acc[k][0] = acc[k][1] = acc[k][2] = acc[k][3] = 0.f; }
#pragma unroll 2
    for (int f = 0; f < FCH; f += 4) {
        float4 s0 = *(const float4*)(sb + (size_t)(f + 0) * TT);
        float4 s1 = *(const float4*)(sb + (size_t)(f + 1) * TT);
        float4 s2 = *(const float4*)(sb + (size_t)(f + 2) * TT);
        float4 s3 = *(const float4*)(sb + (size_t)(f + 3) * TT);
#pragma unroll
        for (int k = 0; k < OPER; ++k) {
            float4 wv = *(const float4*)(wb + (size_t)(og * OPER + k) * FIN + f);
            acc[k][0] += wv.x * s0.x + wv.y * s1.x + wv.z * s2.x + wv.w * s3.x;
            acc[k][1] += wv.x * s0.y + wv.y * s1.y + wv.z * s2.y + wv.w * s3.y;
            acc[k][2] += wv.x * s0.z + wv.y * s1.z + wv.z * s2.z + wv.w * s3.z;
            acc[k][3] += wv.x * s0.w + wv.y * s1.w + wv.z * s2.w + wv.w * s3.w;
        }
    }
#pragma unroll
    for (int k = 0; k < OPER; ++k) {
        float4 o; o.x = acc[k][0]; o.y = acc[k][1]; o.z = acc[k][2]; o.w = acc[k][3];
        *(float4*)(z + ((size_t)sp * NBATCH * OUT + (size_t)n * OUT + og * OPER + k) * TT + tc * 4) = o;
    }
}

extern "C" void kernel_launch(void* const* d_in, const int* in_sizes, int n_in,
                              void* d_out, int out_size, void* d_ws, size_t ws_size,
                              hipStream_t stream) {
    const float* s_in = (const float*)d_in[0]; // (4,2,128,128,300)
    const float* w1   = (const float*)d_in[1]; // (32,2,5,5)
    const float* w2   = (const float*)d_in[2]; // (64,32,3,3)
    const float* w3   = (const float*)d_in[3]; // (64,64,3,3)
    const float* w4a  = (const float*)d_in[4]; // (256,4096)
    const float* w4b  = (const float*)d_in[5]; // (11,256)
    float* out = (float*)d_out;                // (4,11,300)

    // Workspace (floats): Z 39,321,600 | Sb 9,830,400 (time-multiplexed spikes) | packed w.
    float* Z  = (float*)d_ws;
    float* Sb = Z + 39321600;
    float* WP = Sb + 9830400;
    float* w1p = WP;           // 50*32   = 1600
    float* w2p = WP + 1600;    // 288*64  = 18432
    float* w3p = WP + 20032;   // 576*64  = 36864

    auto g = [](int n) { return (n + 255) / 256; };
    auto g64 = [](int n) { return (n + 63) / 64; };

    k_pack_w<<<g(1600),  256, 0, stream>>>(w1, w1p, 50, 32, 1600);
    k_pack_w<<<g(18432), 256, 0, stream>>>(w2, w2p, 288, 64, 18432);
    k_pack_w<<<g(36864), 256, 0, stream>>>(w3, w3p, 576, 64, 36864);

    // L0: 4x4 pool + psp -> s0 (4,2,32,32,300) @ Sb
    k_pool4<<<g(614400), 256, 0, stream>>>(s_in, Z);
    k_scan_redp<1><<<g64(8192), 64, 0, stream>>>(Z, Sb, 8192, 0);

    // L1 conv 5x5 (2->32, 32x32): z1 (39.3M) @ Z. 1200 blocks x 512.
    k_conv_lds<1, 2, 32, 32, 32, 5, 2><<<1200, 512, 0, stream>>>(Sb, w1p, Z);
    // L1 psp + 2x2 pool + L2 psp -> s2 (4,32,16,16,300) @ Sb. 512 blocks.
    k_spsq<1, 32, 16, 16><<<512, 256, 0, stream>>>(Z, Sb, 0);

    // L3 conv 3x3 (32->64, 16x16), ci-split 2: z3 (2 x 19.66M) @ Z. 1200 blocks x 512.
    k_conv_lds<2, 32, 64, 16, 16, 3, 1><<<1200, 512, 0, stream>>>(Sb, w2p, Z);
    // L3 psp + 2x2 pool + L4 psp -> s4 (4,64,8,8,300) @ Sb. 256 blocks.
    k_spsq<2, 64, 8, 8><<<256, 256, 0, stream>>>(Z, Sb, 19660800);

    // L5 conv 3x3 (64->64, 8x8), ci-split 4: z5 (4 x 4.92M) @ Z. 600 blocks x 512.
    k_conv_lds<4, 64, 64, 8, 8, 3, 1><<<600, 512, 0, stream>>>(Sb, w3p, Z);
    // fused 4-way reduce + scan -> s5 @ Sb (16384 neurons, 256 blocks of 64)
    k_scan_redp<4><<<g64(16384), 64, 0, stream>>>(Z, Sb, 16384, 4915200);

    // L6: fc 4096->256, 16-way f-split: z6 (16 x 307200) @ Z. 600 blocks.
    k_fc_a<256, 4096, 8, 16><<<600, 256, 0, stream>>>(Sb, w4a, Z);
    k_reduce<16><<<g(76800), 256, 0, stream>>>(Z, Z + 4915200, 76800, 307200);
    k_scan_redp<1><<<g64(1024), 64, 0, stream>>>(Z + 4915200, Sb, 1024, 0);

    // L7: fc 256->11 + psp -> out
    k_fc_a<11, 256, 1, 1><<<g(3300), 256, 0, stream>>>(Sb, w4b, Z);
    k_scan_redp<1><<<1, 64, 0, stream>>>(Z, out, 44, 0);
}

// Round 13
// 773.247 us; speedup vs baseline: 1.0302x; 1.0302x over previous
//
#include <hip/hip_runtime.h>
#include <cstdint>

#define TT 300   // timesteps
#define TC 75    // TT/4
#define NBATCH 4

typedef float pf2 __attribute__((ext_vector_type(2)));   // packs to v_pk_fma_f32

// PSP + refractory IIR step, exact op order of the reference scan.
__device__ __forceinline__ void psp_step(float z, float& gp, float& hp, float& gr, float& hr, float& s_out) {
    hp = 0.90483741803595957f * (hp + gp);      // a_sr = exp(-1/10)
    gp = 0.90483741803595957f * gp + z;
    hr = 0.36787944117144233f * (hr + gr);      // a_rf = exp(-1)
    gr = 0.36787944117144233f * gr;
    float u = 0.27182818284590452f * hp + (-54.365636569180904f) * hr; // c_sr*hp + c_rf*hr
    float s = (u >= 10.0f) ? 1.0f : 0.0f;
    gr += s;
    s_out = s;
}

// Coalesced R-way partial reduce: zr[p][t] = sum_r z[r*pstride + p*TT + t].
template <int R>
__global__ void k_reduce(const float* __restrict__ z, float* __restrict__ zr,
                         int total4, int pstride) {
    int i = blockIdx.x * 256 + threadIdx.x;
    if (i >= total4) return;
    size_t pos = (size_t)i * 4;
    float4 a = *(const float4*)(z + pos);
#pragma unroll
    for (int r = 1; r < R; ++r) {
        float4 b = *(const float4*)(z + (size_t)r * pstride + pos);
        a.x += b.x; a.y += b.y; a.z += b.z; a.w += b.w;
    }
    *(float4*)(zr + pos) = a;
}

// Per-neuron scan over T with fused R-way partial reduce, 12-step chunks (r11 form).
template <int R>
__global__ void k_scan_redp(const float* __restrict__ z, float* __restrict__ s,
                            int n_neur, int pstride) {
    int i = blockIdx.x * 64 + threadIdx.x;
    if (i >= n_neur) return;
    const float* zp = z + (size_t)i * TT;
    float* sp = s + (size_t)i * TT;
    float gp = 0.f, hp = 0.f, gr = 0.f, hr = 0.f;
#pragma unroll 1
    for (int c = 0; c < 25; ++c) {
        const float* p = zp + c * 12;
        float4 a0 = *(const float4*)(p);
        float4 a1 = *(const float4*)(p + 4);
        float4 a2 = *(const float4*)(p + 8);
#pragma unroll
        for (int r = 1; r < R; ++r) {
            const float* pr = p + (size_t)r * pstride;
            float4 b0 = *(const float4*)(pr);
            float4 b1 = *(const float4*)(pr + 4);
            float4 b2 = *(const float4*)(pr + 8);
            a0.x += b0.x; a0.y += b0.y; a0.z += b0.z; a0.w += b0.w;
            a1.x += b1.x; a1.y += b1.y; a1.z += b1.z; a1.w += b1.w;
            a2.x += b2.x; a2.y += b2.y; a2.z += b2.z; a2.w += b2.w;
        }
        float4 o0, o1, o2;
        psp_step(a0.x, gp, hp, gr, hr, o0.x);
        psp_step(a0.y, gp, hp, gr, hr, o0.y);
        psp_step(a0.z, gp, hp, gr, hr, o0.z);
        psp_step(a0.w, gp, hp, gr, hr, o0.w);
        psp_step(a1.x, gp, hp, gr, hr, o1.x);
        psp_step(a1.y, gp, hp, gr, hr, o1.y);
        psp_step(a1.z, gp, hp, gr, hr, o1.z);
        psp_step(a1.w, gp, hp, gr, hr, o1.w);
        psp_step(a2.x, gp, hp, gr, hr, o2.x);
        psp_step(a2.y, gp, hp, gr, hr, o2.y);
        psp_step(a2.z, gp, hp, gr, hr, o2.z);
        psp_step(a2.w, gp, hp, gr, hr, o2.w);
        float* q = sp + c * 12;
        *(float4*)(q) = o0;
        *(float4*)(q + 4) = o1;
        *(float4*)(q + 8) = o2;
    }
}

// Fused scan-pool-scan, thread per CONV neuron; quad pool via shfl_xor (exact on 0/1 spikes).
template <int R, int C, int H2, int W2>
__global__ void __launch_bounds__(256) k_spsq(const float* __restrict__ z,
                                              float* __restrict__ s, int pstride) {
    constexpr int H = 2 * H2, W = 2 * W2;
    int i = blockIdx.x * 256 + threadIdx.x;   // grid exact: NBATCH*C*H*W threads
    int q  = i & 3;
    int p  = i >> 2;
    int x2 = p % W2;
    int y2 = (p / W2) % H2;
    int c  = (p / (W2 * H2)) % C;
    int n  = p / (W2 * H2 * C);
    int dy = q >> 1, dx = q & 1;
    const float* zp = z + (((size_t)(n * C + c) * H + 2 * y2 + dy) * W + 2 * x2 + dx) * TT;
    float* so = s + (size_t)p * TT;
    float gp = 0.f, hp = 0.f, gr = 0.f, hr = 0.f;   // conv neuron IIR
    float Gp = 0.f, Hp = 0.f, Gr = 0.f, Hr = 0.f;   // pooled neuron IIR
#pragma unroll 1
    for (int cc = 0; cc < 25; ++cc) {
        const float* pp = zp + cc * 12;
        float4 a0 = *(const float4*)(pp);
        float4 a1 = *(const float4*)(pp + 4);
        float4 a2 = *(const float4*)(pp + 8);
#pragma unroll
        for (int r = 1; r < R; ++r) {
            const float* pr = pp + (size_t)r * pstride;
            float4 b0 = *(const float4*)(pr);
            float4 b1 = *(const float4*)(pr + 4);
            float4 b2 = *(const float4*)(pr + 8);
            a0.x += b0.x; a0.y += b0.y; a0.z += b0.z; a0.w += b0.w;
            a1.x += b1.x; a1.y += b1.y; a1.z += b1.z; a1.w += b1.w;
            a2.x += b2.x; a2.y += b2.y; a2.z += b2.z; a2.w += b2.w;
        }
        float zv[12] = {a0.x, a0.y, a0.z, a0.w, a1.x, a1.y, a1.z, a1.w, a2.x, a2.y, a2.z, a2.w};
        float ov[12];
#pragma unroll
        for (int tt = 0; tt < 12; ++tt) {
            float sq;
            psp_step(zv[tt], gp, hp, gr, hr, sq);
            float t1 = sq + __shfl_xor(sq, 1, 64);
            float pool = t1 + __shfl_xor(t1, 2, 64);
            psp_step(11.0f * pool, Gp, Hp, Gr, Hr, ov[tt]);
        }
        if (q == 0) {
            float* qo = so + cc * 12;
            *(float4*)(qo)     = make_float4(ov[0], ov[1], ov[2],  ov[3]);
            *(float4*)(qo + 4) = make_float4(ov[4], ov[5], ov[6],  ov[7]);
            *(float4*)(qo + 8) = make_float4(ov[8], ov[9], ov[10], ov[11]);
        }
    }
}

// Transpose-pack OIHW weights (COUT, S) -> [s][COUT] so one tap's weights are contiguous.
__global__ void k_pack_w(const float* __restrict__ w, float* __restrict__ wp, int S, int CO, int total) {
    int i = blockIdx.x * 256 + threadIdx.x;
    if (i >= total) return;
    int co = i % CO, s = i / CO;
    wp[i] = w[co * S + s];
}

// 4x4 sum-pool * 11.0 over (N,2,128,128,T) -> z (N,2,32,32,T). Thread = (p, tc), tc fastest.
__global__ void k_pool4(const float* __restrict__ x, float* __restrict__ z) {
    int idx = blockIdx.x * 256 + threadIdx.x;
    if (idx >= NBATCH * 2 * 32 * 32 * TC) return;
    int tc = idx % TC;
    int p  = idx / TC;
    int w  = p % 32;
    int h  = (p / 32) % 32;
    int nc = p / (32 * 32);
    const float* base = x + (((size_t)nc * 128 + h * 4) * 128 + w * 4) * TT + tc * 4;
    float ax = 0.f, ay = 0.f, az = 0.f, aw = 0.f;
#pragma unroll
    for (int i = 0; i < 4; ++i)
#pragma unroll
        for (int j = 0; j < 4; ++j) {
            float4 v = *(const float4*)(base + ((size_t)i * 128 + j) * TT);
            ax += v.x; ay += v.y; az += v.z; aw += v.w;
        }
    float4 o; o.x = 11.0f * ax; o.y = 11.0f * ay; o.z = 11.0f * az; o.w = 11.0f * aw;
    *(float4*)(z + (size_t)p * TT + tc * 4) = o;
}

// LDS-weight conv (r11 structure: 256 thr, XCD swizzle, cb adjacent to tc) with
// PACKED fp32 FMA: acc held as float2 pairs over the tt dimension so the 64 FMAs/tap
// become 32 v_pk_fma_f32 — halves FMA issue slots (r12 analysis: per-tap issue was
// ~210cyc for 128cyc of FMA -> 60% duty; packing raises the duty ceiling ~1.45x).
// __builtin_elementwise_fma == the contracted v_fmac the compiler already emitted,
// same per-accumulator chain order -> numerics unchanged.
template <int SPLIT, int CIN, int COUT, int H, int W, int K, int PAD>
__global__ void __launch_bounds__(256) k_conv_lds(const float* __restrict__ s_in,
                                                  const float* __restrict__ wp,
                                                  float* __restrict__ z) {
    constexpr int CBN = COUT / 16;
    constexpr int CIN_SP = CIN / SPLIT;
    constexpr int S_SP = CIN_SP * K * K;
    __shared__ float wlds[S_SP * COUT];
    int nb8 = gridDim.x >> 3;
    int lb  = (blockIdx.x >> 3) + (blockIdx.x & 7) * nb8;
    int sp = (int)(((size_t)lb * 256) / (CBN * NBATCH * H * W * TC));
    {
        const float4* src = (const float4*)(wp + (size_t)sp * S_SP * COUT);
        float4* dst = (float4*)wlds;
        for (int i = threadIdx.x; i < S_SP * COUT / 4; i += 256) dst[i] = src[i];
    }
    __syncthreads();
    int t = lb * 256 + threadIdx.x;
    int tc = t % TC;     t /= TC;
    int cb = t % CBN;    t /= CBN;
    int x  = t % W;      t /= W;
    int y  = t % H;      t /= H;
    int n  = t % NBATCH;
    const float* sb = s_in + ((size_t)n * CIN + sp * CIN_SP) * H * W * TT + tc * 4;
    pf2 acc[4][4][2]; // [cg][c][tt-pair]
#pragma unroll
    for (int a = 0; a < 4; ++a)
#pragma unroll
        for (int b = 0; b < 4; ++b)
#pragma unroll
            for (int d = 0; d < 2; ++d) acc[a][b][d] = (pf2){0.f, 0.f};
#pragma unroll 1
    for (int cl = 0; cl < CIN_SP; ++cl) {
#pragma unroll
        for (int ky = 0; ky < K; ++ky) {
            int yy = y + ky - PAD;
            if (yy < 0 || yy >= H) continue;
#pragma unroll
            for (int kx = 0; kx < K; ++kx) {
                int xx = x + kx - PAD;
                if (xx < 0 || xx >= W) continue;
                float4 v = *(const float4*)(sb + ((size_t)(cl * H + yy) * W + xx) * TT);
                pf2 v01 = {v.x, v.y}, v23 = {v.z, v.w};
                const float* wrow = &wlds[((cl * K + ky) * K + kx) * COUT + cb * 16];
#pragma unroll
                for (int cg = 0; cg < 4; ++cg) {
                    float4 wv = *(const float4*)(wrow + cg * 4);
                    float wa[4] = {wv.x, wv.y, wv.z, wv.w};
#pragma unroll
                    for (int c = 0; c < 4; ++c) {
                        pf2 w2 = {wa[c], wa[c]};
                        acc[cg][c][0] = __builtin_elementwise_fma(w2, v01, acc[cg][c][0]);
                        acc[cg][c][1] = __builtin_elementwise_fma(w2, v23, acc[cg][c][1]);
                    }
                }
            }
        }
    }
    float* zb = z + (((size_t)(sp * NBATCH + n) * COUT + cb * 16) * H * W + (size_t)y * W + x) * TT + tc * 4;
#pragma unroll
    for (int cg = 0; cg < 4; ++cg)
#pragma unroll
        for (int c = 0; c < 4; ++c) {
            float4 o;
            o.x = acc[cg][c][0].x; o.y = acc[cg][c][0].y;
            o.z = acc[cg][c][1].x; o.w = acc[cg][c][1].y;
            *(float4*)(zb + (size_t)(cg * 4 + c) * H * W * TT) = o;
        }
}

// FC with f-split, packed fp32 FMA over the t dimension (same chain order per output).
template <int OUT, int FIN, int OPER, int FSPLIT>
__global__ void k_fc_a(const float* __restrict__ s, const float* __restrict__ wgt,
                       float* __restrict__ z) {
    constexpr int OG = OUT / OPER, FCH = FIN / FSPLIT;
    int idx = blockIdx.x * 256 + threadIdx.x;
    if (idx >= NBATCH * OG * TC * FSPLIT) return;
    int tc = idx % TC;
    int og = (idx / TC) % OG;
    int n  = (idx / (TC * OG)) % NBATCH;
    int sp = idx / (TC * OG * NBATCH);
    const float* sb = s + (size_t)n * FIN * TT + (size_t)sp * FCH * TT + tc * 4;
    const float* wb = wgt + (size_t)sp * FCH;
    pf2 acc[OPER][2];
#pragma unroll
    for (int k = 0; k < OPER; ++k) { acc[k][0] = (pf2){0.f, 0.f}; acc[k][1] = (pf2){0.f, 0.f}; }
#pragma unroll 2
    for (int f = 0; f < FCH; f += 4) {
        float4 s0 = *(const float4*)(sb + (size_t)(f + 0) * TT);
        float4 s1 = *(const float4*)(sb + (size_t)(f + 1) * TT);
        float4 s2 = *(const float4*)(sb + (size_t)(f + 2) * TT);
        float4 s3 = *(const float4*)(sb + (size_t)(f + 3) * TT);
        pf2 s0a = {s0.x, s0.y}, s0b = {s0.z, s0.w};
        pf2 s1a = {s1.x, s1.y}, s1b = {s1.z, s1.w};
        pf2 s2a = {s2.x, s2.y}, s2b = {s2.z, s2.w};
        pf2 s3a = {s3.x, s3.y}, s3b = {s3.z, s3.w};
#pragma unroll
        for (int k = 0; k < OPER; ++k) {
            float4 wv = *(const float4*)(wb + (size_t)(og * OPER + k) * FIN + f);
            pf2 wx = {wv.x, wv.x}, wy = {wv.y, wv.y}, wz = {wv.z, wv.z}, ww = {wv.w, wv.w};
            pf2 a0 = acc[k][0], a1 = acc[k][1];
            a0 = __builtin_elementwise_fma(wx, s0a, a0);
            a0 = __builtin_elementwise_fma(wy, s1a, a0);
            a0 = __builtin_elementwise_fma(wz, s2a, a0);
            a0 = __builtin_elementwise_fma(ww, s3a, a0);
            a1 = __builtin_elementwise_fma(wx, s0b, a1);
            a1 = __builtin_elementwise_fma(wy, s1b, a1);
            a1 = __builtin_elementwise_fma(wz, s2b, a1);
            a1 = __builtin_elementwise_fma(ww, s3b, a1);
            acc[k][0] = a0; acc[k][1] = a1;
        }
    }
#pragma unroll
    for (int k = 0; k < OPER; ++k) {
        float4 o;
        o.x = acc[k][0].x; o.y = acc[k][0].y; o.z = acc[k][1].x; o.w = acc[k][1].y;
        *(float4*)(z + ((size_t)sp * NBATCH * OUT + (size_t)n * OUT + og * OPER + k) * TT + tc * 4) = o;
    }
}

extern "C" void kernel_launch(void* const* d_in, const int* in_sizes, int n_in,
                              void* d_out, int out_size, void* d_ws, size_t ws_size,
                              hipStream_t stream) {
    const float* s_in = (const float*)d_in[0]; // (4,2,128,128,300)
    const float* w1   = (const float*)d_in[1]; // (32,2,5,5)
    const float* w2   = (const float*)d_in[2]; // (64,32,3,3)
    const float* w3   = (const float*)d_in[3]; // (64,64,3,3)
    const float* w4a  = (const float*)d_in[4]; // (256,4096)
    const float* w4b  = (const float*)d_in[5]; // (11,256)
    float* out = (float*)d_out;                // (4,11,300)

    // Workspace (floats): Z 39,321,600 | Sb 9,830,400 (time-multiplexed spikes) | packed w.
    float* Z  = (float*)d_ws;
    float* Sb = Z + 39321600;
    float* WP = Sb + 9830400;
    float* w1p = WP;           // 50*32   = 1600
    float* w2p = WP + 1600;    // 288*64  = 18432
    float* w3p = WP + 20032;   // 576*64  = 36864

    auto g = [](int n) { return (n + 255) / 256; };
    auto g64 = [](int n) { return (n + 63) / 64; };

    k_pack_w<<<g(1600),  256, 0, stream>>>(w1, w1p, 50, 32, 1600);
    k_pack_w<<<g(18432), 256, 0, stream>>>(w2, w2p, 288, 64, 18432);
    k_pack_w<<<g(36864), 256, 0, stream>>>(w3, w3p, 576, 64, 36864);

    // L0: 4x4 pool + psp -> s0 (4,2,32,32,300) @ Sb
    k_pool4<<<g(614400), 256, 0, stream>>>(s_in, Z);
    k_scan_redp<1><<<g64(8192), 64, 0, stream>>>(Z, Sb, 8192, 0);

    // L1 conv 5x5 (2->32, 32x32): z1 (39.3M) @ Z. 2400 blocks exact.
    k_conv_lds<1, 2, 32, 32, 32, 5, 2><<<2400, 256, 0, stream>>>(Sb, w1p, Z);
    // L1 psp + 2x2 pool + L2 psp -> s2 (4,32,16,16,300) @ Sb. 512 blocks.
    k_spsq<1, 32, 16, 16><<<512, 256, 0, stream>>>(Z, Sb, 0);

    // L3 conv 3x3 (32->64, 16x16), ci-split 2: z3 (2 x 19.66M) @ Z. 2400 blocks exact.
    k_conv_lds<2, 32, 64, 16, 16, 3, 1><<<2400, 256, 0, stream>>>(Sb, w2p, Z);
    // L3 psp + 2x2 pool + L4 psp -> s4 (4,64,8,8,300) @ Sb. 256 blocks.
    k_spsq<2, 64, 8, 8><<<256, 256, 0, stream>>>(Z, Sb, 19660800);

    // L5 conv 3x3 (64->64, 8x8), ci-split 4: z5 (4 x 4.92M) @ Z. 1200 blocks exact.
    k_conv_lds<4, 64, 64, 8, 8, 3, 1><<<1200, 256, 0, stream>>>(Sb, w3p, Z);
    // fused 4-way reduce + scan -> s5 @ Sb (16384 neurons, 256 blocks of 64)
    k_scan_redp<4><<<g64(16384), 64, 0, stream>>>(Z, Sb, 16384, 4915200);

    // L6: fc 4096->256, 16-way f-split: z6 (16 x 307200) @ Z. 600 blocks.
    k_fc_a<256, 4096, 8, 16><<<600, 256, 0, stream>>>(Sb, w4a, Z);
    k_reduce<16><<<g(76800), 256, 0, stream>>>(Z, Z + 4915200, 76800, 307200);
    k_scan_redp<1><<<g64(1024), 64, 0, stream>>>(Z + 4915200, Sb, 1024, 0);

    // L7: fc 256->11 + psp -> out
    k_fc_a<11, 256, 1, 1><<<g(3300), 256, 0, stream>>>(Sb, w4b, Z);
    k_scan_redp<1><<<1, 64, 0, stream>>>(Z, out, 44, 0);
}